// Round 2
// baseline (126.970 us; speedup 1.0000x reference)
//
#include <hip/hip_runtime.h>

#define RES 96
#define CENTER 48
#define NPIX (RES * RES)
#define EPSF 1e-5f

// ---------------------------------------------------------------------------
// REAL kernel — byte-identical to the current best (61.06 us harness result).
// ---------------------------------------------------------------------------
__global__ __launch_bounds__(256) void topos_kernel(const float* __restrict__ src,
                                                    float* __restrict__ out) {
    const int tid = threadIdx.x;
    const int wave = tid >> 6;
    const int lane = tid & 63;
    const int pix0 = blockIdx.x * 4;     // 2304 groups
    const int i = pix0 / RES;            // all 4 pixels share this row
    const int j0 = pix0 - i * RES;       // multiple of 4

    __shared__ float partial[16];        // [wave][pixel]

    float z2[4];
    bool allrim = true;
    #pragma unroll
    for (int p = 0; p < 4; ++p) {
        const int dj = j0 + p - CENTER;
        const int r2 = (i - CENTER) * (i - CENTER) + dj * dj;
        allrim &= (r2 >= (CENTER - 1) * (CENTER - 1));
        const float z = (float)CENTER - sqrtf((float)r2) + EPSF;
        z2[p] = z * z;
    }

    if (allrim) {  // whole group is rim: pure pass-through, block exits
        if (tid < 4) out[pix0 + tid] = src[pix0 + tid];
        return;
    }

    const int s0 = wave * 256 + lane * 4;
    const int biq0 = s0 / RES;           // 0..10
    const int bjq0 = s0 - biq0 * RES;
    float fdi = (float)(i - biq0);
    float y = (float)(j0 - bjq0);
    const float wraplim = (float)(j0 - 95);
    const float* ptr = src + s0;

    float acc0 = 0.f, acc1 = 0.f, acc2 = 0.f, acc3 = 0.f;

    #pragma unroll 3
    for (int it = 0; it < 9; ++it, ptr += 1024) {
        const float4 b4 = *(const float4*)ptr;
        const float w0 = fmaxf(b4.x, 0.f);
        const float w1 = fmaxf(b4.y, 0.f);
        const float w2 = fmaxf(b4.z, 0.f);
        const float w3 = fmaxf(b4.w, 0.f);

        const float s2 = fdi * fdi;
        const float vm3 = y - 3.f, vm2 = y - 2.f, vm1 = y - 1.f;
        const float vp1 = y + 1.f, vp2 = y + 2.f, vp3 = y + 3.f;

        {
            const float t = s2 + z2[0];
            const float d0 = fmaf(y, y, t),     d1 = fmaf(vm1, vm1, t);
            const float d2 = fmaf(vm2, vm2, t), d3 = fmaf(vm3, vm3, t);
            const float d01 = d0 * d1, d23 = d2 * d3;
            const float n01 = fmaf(w0, d1, w1 * d0);
            const float n23 = fmaf(w2, d3, w3 * d2);
            acc0 = fmaf(fmaf(n01, d23, n23 * d01),
                        __builtin_amdgcn_rcpf(d01 * d23), acc0);
        }
        {
            const float t = s2 + z2[1];
            const float d0 = fmaf(vp1, vp1, t), d1 = fmaf(y, y, t);
            const float d2 = fmaf(vm1, vm1, t), d3 = fmaf(vm2, vm2, t);
            const float d01 = d0 * d1, d23 = d2 * d3;
            const float n01 = fmaf(w0, d1, w1 * d0);
            const float n23 = fmaf(w2, d3, w3 * d2);
            acc1 = fmaf(fmaf(n01, d23, n23 * d01),
                        __builtin_amdgcn_rcpf(d01 * d23), acc1);
        }
        {
            const float t = s2 + z2[2];
            const float d0 = fmaf(vp2, vp2, t), d1 = fmaf(vp1, vp1, t);
            const float d2 = fmaf(y, y, t),     d3 = fmaf(vm1, vm1, t);
            const float d01 = d0 * d1, d23 = d2 * d3;
            const float n01 = fmaf(w0, d1, w1 * d0);
            const float n23 = fmaf(w2, d3, w3 * d2);
            acc2 = fmaf(fmaf(n01, d23, n23 * d01),
                        __builtin_amdgcn_rcpf(d01 * d23), acc2);
        }
        {
            const float t = s2 + z2[3];
            const float d0 = fmaf(vp3, vp3, t), d1 = fmaf(vp2, vp2, t);
            const float d2 = fmaf(vp1, vp1, t), d3 = fmaf(y, y, t);
            const float d01 = d0 * d1, d23 = d2 * d3;
            const float n01 = fmaf(w0, d1, w1 * d0);
            const float n23 = fmaf(w2, d3, w3 * d2);
            acc3 = fmaf(fmaf(n01, d23, n23 * d01),
                        __builtin_amdgcn_rcpf(d01 * d23), acc3);
        }

        y -= 64.f;
        const bool wr = y < wraplim;
        y = wr ? y + 96.f : y;
        fdi -= wr ? 11.f : 10.f;
    }

    #pragma unroll
    for (int off = 32; off > 0; off >>= 1) {
        acc0 += __shfl_down(acc0, off, 64);
        acc1 += __shfl_down(acc1, off, 64);
        acc2 += __shfl_down(acc2, off, 64);
        acc3 += __shfl_down(acc3, off, 64);
    }

    if (lane == 0) {
        partial[wave * 4 + 0] = acc0;
        partial[wave * 4 + 1] = acc1;
        partial[wave * 4 + 2] = acc2;
        partial[wave * 4 + 3] = acc3;
    }
    __syncthreads();

    if (tid < 4) {
        const float sum = (partial[tid] + partial[4 + tid])
                        + (partial[8 + tid] + partial[12 + tid]);
        const int dj = j0 + tid - CENTER;
        const int r2 = (i - CENTER) * (i - CENTER) + dj * dj;
        const bool rim = r2 >= (CENTER - 1) * (CENTER - 1);
        out[pix0 + tid] = rim ? src[pix0 + tid] : sum;
    }
}

// ---------------------------------------------------------------------------
// DIAGNOSTIC kernel — faithful replica of the loop, repeated REPS times so the
// dispatch exceeds the ~39.5 us poison fills and enters rocprof's top-5 with
// full counters (VALUBusy / VGPR_Count / OccupancyPercent / FETCH_SIZE for
// this exact loop body). Writes to workspace only; `out` comes solely from
// topos_kernel above. Per-rep "memory"-clobber asm forces real reloads
// (anti-CSE); acc sink keeps each rep live (anti-DCE, guide rule #17).
// ---------------------------------------------------------------------------
template<int REPS>
__global__ __launch_bounds__(256) void topos_diag(const float* __restrict__ src,
                                                  float* __restrict__ outws) {
    const int tid = threadIdx.x;
    const int wave = tid >> 6;
    const int lane = tid & 63;
    const int pix0 = blockIdx.x * 4;
    const int i = pix0 / RES;
    const int j0 = pix0 - i * RES;

    __shared__ float partial[16];

    float z2[4];
    bool allrim = true;
    #pragma unroll
    for (int p = 0; p < 4; ++p) {
        const int dj = j0 + p - CENTER;
        const int r2 = (i - CENTER) * (i - CENTER) + dj * dj;
        allrim &= (r2 >= (CENTER - 1) * (CENTER - 1));
        const float z = (float)CENTER - sqrtf((float)r2) + EPSF;
        z2[p] = z * z;
    }

    if (allrim) {
        if (tid < 4) outws[pix0 + tid] = src[pix0 + tid];
        return;
    }

    const int s0 = wave * 256 + lane * 4;
    const int biq0 = s0 / RES;
    const int bjq0 = s0 - biq0 * RES;
    const float fdi0 = (float)(i - biq0);
    const float y0 = (float)(j0 - bjq0);
    const float wraplim = (float)(j0 - 95);

    float acc0 = 0.f, acc1 = 0.f, acc2 = 0.f, acc3 = 0.f;

    #pragma unroll 1
    for (int rep = 0; rep < REPS; ++rep) {
        float y = y0, fdi = fdi0;
        // opaque seeds + memory clobber: each rep recomputes and reloads
        asm volatile("" : "+v"(y), "+v"(fdi) :: "memory");
        const float* ptr = src + s0;
        acc0 = 0.f; acc1 = 0.f; acc2 = 0.f; acc3 = 0.f;

        #pragma unroll 3
        for (int it = 0; it < 9; ++it, ptr += 1024) {
            const float4 b4 = *(const float4*)ptr;
            const float w0 = fmaxf(b4.x, 0.f);
            const float w1 = fmaxf(b4.y, 0.f);
            const float w2 = fmaxf(b4.z, 0.f);
            const float w3 = fmaxf(b4.w, 0.f);

            const float s2 = fdi * fdi;
            const float vm3 = y - 3.f, vm2 = y - 2.f, vm1 = y - 1.f;
            const float vp1 = y + 1.f, vp2 = y + 2.f, vp3 = y + 3.f;

            {
                const float t = s2 + z2[0];
                const float d0 = fmaf(y, y, t),     d1 = fmaf(vm1, vm1, t);
                const float d2 = fmaf(vm2, vm2, t), d3 = fmaf(vm3, vm3, t);
                const float d01 = d0 * d1, d23 = d2 * d3;
                const float n01 = fmaf(w0, d1, w1 * d0);
                const float n23 = fmaf(w2, d3, w3 * d2);
                acc0 = fmaf(fmaf(n01, d23, n23 * d01),
                            __builtin_amdgcn_rcpf(d01 * d23), acc0);
            }
            {
                const float t = s2 + z2[1];
                const float d0 = fmaf(vp1, vp1, t), d1 = fmaf(y, y, t);
                const float d2 = fmaf(vm1, vm1, t), d3 = fmaf(vm2, vm2, t);
                const float d01 = d0 * d1, d23 = d2 * d3;
                const float n01 = fmaf(w0, d1, w1 * d0);
                const float n23 = fmaf(w2, d3, w3 * d2);
                acc1 = fmaf(fmaf(n01, d23, n23 * d01),
                            __builtin_amdgcn_rcpf(d01 * d23), acc1);
            }
            {
                const float t = s2 + z2[2];
                const float d0 = fmaf(vp2, vp2, t), d1 = fmaf(vp1, vp1, t);
                const float d2 = fmaf(y, y, t),     d3 = fmaf(vm1, vm1, t);
                const float d01 = d0 * d1, d23 = d2 * d3;
                const float n01 = fmaf(w0, d1, w1 * d0);
                const float n23 = fmaf(w2, d3, w3 * d2);
                acc2 = fmaf(fmaf(n01, d23, n23 * d01),
                            __builtin_amdgcn_rcpf(d01 * d23), acc2);
            }
            {
                const float t = s2 + z2[3];
                const float d0 = fmaf(vp3, vp3, t), d1 = fmaf(vp2, vp2, t);
                const float d2 = fmaf(vp1, vp1, t), d3 = fmaf(y, y, t);
                const float d01 = d0 * d1, d23 = d2 * d3;
                const float n01 = fmaf(w0, d1, w1 * d0);
                const float n23 = fmaf(w2, d3, w3 * d2);
                acc3 = fmaf(fmaf(n01, d23, n23 * d01),
                            __builtin_amdgcn_rcpf(d01 * d23), acc3);
            }

            y -= 64.f;
            const bool wr = y < wraplim;
            y = wr ? y + 96.f : y;
            fdi -= wr ? 11.f : 10.f;
        }

        // keep every rep's results live without cost (anti-DCE sink)
        asm volatile("" :: "v"(acc0), "v"(acc1), "v"(acc2), "v"(acc3));
    }

    #pragma unroll
    for (int off = 32; off > 0; off >>= 1) {
        acc0 += __shfl_down(acc0, off, 64);
        acc1 += __shfl_down(acc1, off, 64);
        acc2 += __shfl_down(acc2, off, 64);
        acc3 += __shfl_down(acc3, off, 64);
    }

    if (lane == 0) {
        partial[wave * 4 + 0] = acc0;
        partial[wave * 4 + 1] = acc1;
        partial[wave * 4 + 2] = acc2;
        partial[wave * 4 + 3] = acc3;
    }
    __syncthreads();

    if (tid < 4) {
        const float sum = (partial[tid] + partial[4 + tid])
                        + (partial[8 + tid] + partial[12 + tid]);
        outws[pix0 + tid] = sum;
    }
}

extern "C" void kernel_launch(void* const* d_in, const int* in_sizes, int n_in,
                              void* d_out, int out_size, void* d_ws, size_t ws_size,
                              hipStream_t stream) {
    const float* src = (const float*)d_in[0];
    float* out = (float*)d_out;
    float* ws = (float*)d_ws;

    // real result (unchanged)
    topos_kernel<<<NPIX / 4, 256, 0, stream>>>(src, out);

    // diagnostic: faithful loop x8 (~170us) -> enters rocprof top-5 with the
    // real loop body's counters. Workspace-only writes.
    topos_diag<8><<<NPIX / 4, 256, 0, stream>>>(src, ws);
}

// Round 3
// 61.606 us; speedup vs baseline: 2.0610x; 2.0610x over previous
//
#include <hip/hip_runtime.h>

#define RES 96
#define CENTER 48
#define NPIX (RES * RES)
#define EPSF 1e-5f

// Block = 192 threads = 3 waves = ONE 4-pixel group (pix0 = blockIdx*4, same
// row). Wave w's lane-quad starts at s0 = w*256 + lane*4 (0..764) and strides
// +768 floats for 12 iterations (768*12 = 9216 sources).
//
// KEY: 768 = 8*96 exactly -> the quad's COLUMN is loop-invariant (bj fixed,
// bi += 8/iter). So y and the seven u-deltas (y-3..y+3) hoist out of the loop
// and the old wrap/cndmask block (5 instr) disappears: ~68 VALU/iter vs ~78.
// Also 2304 blocks * 3 waves = 27 waves/CU < 32-wave cap -> ALL blocks
// co-resident, no serialized 9th-block tail (the old 4-wave layout needed 36).
// One rcp per 4 sources per pixel via rational combining (unchanged math:
// d = fmaf(u,u, fdi^2+z2[p]) bitwise as before). Explicit next-iter register
// prefetch hides L2 latency (VALUBusy was 75% -> target ~85%).
__global__ __launch_bounds__(192, 8) void topos_kernel(const float* __restrict__ src,
                                                       float* __restrict__ out) {
    const int tid = threadIdx.x;
    const int wave = tid >> 6;           // 0..2
    const int lane = tid & 63;
    const int pix0 = blockIdx.x * 4;     // 2304 groups
    const int i = pix0 / RES;            // all 4 pixels share this row
    const int j0 = pix0 - i * RES;       // multiple of 4

    __shared__ float partial[12];        // [wave][pixel]

    // per-pixel rim flag and z^2 (exact int rim test)
    float z2[4];
    bool allrim = true;
    #pragma unroll
    for (int p = 0; p < 4; ++p) {
        const int dj = j0 + p - CENTER;
        const int r2 = (i - CENTER) * (i - CENTER) + dj * dj;
        allrim &= (r2 >= (CENTER - 1) * (CENTER - 1));
        const float z = (float)CENTER - sqrtf((float)r2) + EPSF;
        z2[p] = z * z;
    }

    if (allrim) {  // whole group is rim: pure pass-through, block exits
        if (tid < 4) out[pix0 + tid] = src[pix0 + tid];
        return;
    }

    // wave w's lane-quad: 4-aligned, never straddles a row (96 % 4 == 0)
    const int s0 = wave * 256 + lane * 4;
    const int biq0 = s0 / RES;           // 0..7
    const int bjq0 = s0 - biq0 * RES;
    float fdi = (float)(i - biq0);       // row delta; -8 per iteration
    const float y = (float)(j0 - bjq0);  // column delta: LOOP-INVARIANT

    // 7 loop-invariant column deltas u_m = y + m, m in [-3,3]
    const float um3 = y - 3.f, um2 = y - 2.f, um1 = y - 1.f;
    const float up1 = y + 1.f, up2 = y + 2.f, up3 = y + 3.f;

    const float* ptr = src + s0;
    float4 b4 = *(const float4*)ptr;     // iteration-0 sources

    float acc0 = 0.f, acc1 = 0.f, acc2 = 0.f, acc3 = 0.f;

    #pragma unroll 3
    for (int it = 0; it < 12; ++it) {
        // prefetch next iteration's quad (last iter: harmless same-addr reread)
        const float* pnext = ptr + (it < 11 ? 768 : 0);
        const float4 bn = *(const float4*)pnext;

        const float w0 = fmaxf(b4.x, 0.f);
        const float w1 = fmaxf(b4.y, 0.f);
        const float w2 = fmaxf(b4.z, 0.f);
        const float w3 = fmaxf(b4.w, 0.f);

        const float s2 = fdi * fdi;
        const float t0 = s2 + z2[0];
        const float t1 = s2 + z2[1];
        const float t2 = s2 + z2[2];
        const float t3 = s2 + z2[3];

        // pixel 0: u = { y, um1, um2, um3 }
        {
            const float d0 = fmaf(y, y, t0),     d1 = fmaf(um1, um1, t0);
            const float d2 = fmaf(um2, um2, t0), d3 = fmaf(um3, um3, t0);
            const float d01 = d0 * d1, d23 = d2 * d3;
            const float n01 = fmaf(w0, d1, w1 * d0);
            const float n23 = fmaf(w2, d3, w3 * d2);
            acc0 = fmaf(fmaf(n01, d23, n23 * d01),
                        __builtin_amdgcn_rcpf(d01 * d23), acc0);
        }
        // pixel 1: u = { up1, y, um1, um2 }
        {
            const float d0 = fmaf(up1, up1, t1), d1 = fmaf(y, y, t1);
            const float d2 = fmaf(um1, um1, t1), d3 = fmaf(um2, um2, t1);
            const float d01 = d0 * d1, d23 = d2 * d3;
            const float n01 = fmaf(w0, d1, w1 * d0);
            const float n23 = fmaf(w2, d3, w3 * d2);
            acc1 = fmaf(fmaf(n01, d23, n23 * d01),
                        __builtin_amdgcn_rcpf(d01 * d23), acc1);
        }
        // pixel 2: u = { up2, up1, y, um1 }
        {
            const float d0 = fmaf(up2, up2, t2), d1 = fmaf(up1, up1, t2);
            const float d2 = fmaf(y, y, t2),     d3 = fmaf(um1, um1, t2);
            const float d01 = d0 * d1, d23 = d2 * d3;
            const float n01 = fmaf(w0, d1, w1 * d0);
            const float n23 = fmaf(w2, d3, w3 * d2);
            acc2 = fmaf(fmaf(n01, d23, n23 * d01),
                        __builtin_amdgcn_rcpf(d01 * d23), acc2);
        }
        // pixel 3: u = { up3, up2, up1, y }
        {
            const float d0 = fmaf(up3, up3, t3), d1 = fmaf(up2, up2, t3);
            const float d2 = fmaf(up1, up1, t3), d3 = fmaf(y, y, t3);
            const float d01 = d0 * d1, d23 = d2 * d3;
            const float n01 = fmaf(w0, d1, w1 * d0);
            const float n23 = fmaf(w2, d3, w3 * d2);
            acc3 = fmaf(fmaf(n01, d23, n23 * d01),
                        __builtin_amdgcn_rcpf(d01 * d23), acc3);
        }

        fdi -= 8.f;      // bi += 8, bj unchanged — no wrap logic
        ptr = pnext;
        b4 = bn;
    }

    // wave reductions (4 independent chains interleave)
    #pragma unroll
    for (int off = 32; off > 0; off >>= 1) {
        acc0 += __shfl_down(acc0, off, 64);
        acc1 += __shfl_down(acc1, off, 64);
        acc2 += __shfl_down(acc2, off, 64);
        acc3 += __shfl_down(acc3, off, 64);
    }

    if (lane == 0) {
        partial[wave * 4 + 0] = acc0;
        partial[wave * 4 + 1] = acc1;
        partial[wave * 4 + 2] = acc2;
        partial[wave * 4 + 3] = acc3;
    }
    __syncthreads();

    if (tid < 4) {
        const float sum = partial[tid] + partial[4 + tid] + partial[8 + tid];
        // recompute this pixel's rim flag (exact int test)
        const int dj = j0 + tid - CENTER;
        const int r2 = (i - CENTER) * (i - CENTER) + dj * dj;
        const bool rim = r2 >= (CENTER - 1) * (CENTER - 1);
        out[pix0 + tid] = rim ? src[pix0 + tid] : sum;
    }
}

extern "C" void kernel_launch(void* const* d_in, const int* in_sizes, int n_in,
                              void* d_out, int out_size, void* d_ws, size_t ws_size,
                              hipStream_t stream) {
    const float* src = (const float*)d_in[0];
    float* out = (float*)d_out;
    // 2304 blocks x 192 threads: 9 blocks/CU, 27 waves/CU -> all co-resident
    topos_kernel<<<NPIX / 4, 192, 0, stream>>>(src, out);
}